// Round 5
// baseline (193.997 us; speedup 1.0000x reference)
//
#include <hip/hip_runtime.h>
#include <hip/hip_bf16.h>

// out[t][e] = (W[e][ids[t]] + b[e]) * sqrt(512)
// W: (512, 50257) row-major f32; ids: 32768 int32; out: 32768 x 512 f32.
//
// Round 5: granule experiment. Same inverted-index + DMA-staged transpose-
// scatter as r4, but vocab slice per bucket VB: 32 -> 64, so each staged
// W-row run is 256 B contiguous (vs 128 B). Blocks split EMB in two panels
// to keep grid ~1572 and LDS ~33 KB (4 blocks/CU, 16 waves) identical to r4.
// Theory: scattered-128B fetch is DRAM-page-bound at ~3 TB/s; 256 B runs
// should roughly double page efficiency.

constexpr int VOCAB = 50257;
constexpr int EMB   = 512;
constexpr int NTOK  = 8 * 4096;
constexpr float SCALE = 22.62741699796952f;  // sqrt(512)

constexpr int VB  = 64;                    // vocab ids per bucket (256 B runs)
constexpr int NB  = (VOCAB + VB - 1) / VB; // 786 buckets
constexpr int CAP = 128;                   // bucket capacity (mean 41.7, sigma 6.4)
constexpr int EPB = 256;                   // e-panel per block (2 panels/bucket)
constexpr int ECH = 128;                   // e-chunk per stage pass

// d_ws int layout: counts[NB] | ocount[1] | olist[NTOK] | buckets[NB*CAP]

__global__ __launch_bounds__(256) void init_counts(int* __restrict__ counts) {
    int i = blockIdx.x * 256 + threadIdx.x;
    if (i < NB + 1) counts[i] = 0;
}

__global__ __launch_bounds__(256) void build_buckets(
    const int* __restrict__ ids,
    int* __restrict__ counts,
    int* __restrict__ olist,
    int* __restrict__ buckets)
{
    int t = blockIdx.x * 256 + threadIdx.x;
    int id = ids[t];
    int bkt = id >> 6;                      // VB = 64
    int slot = atomicAdd(&counts[bkt], 1);
    if (slot < CAP) {
        buckets[bkt * CAP + slot] = (t << 6) | (id & 63);
    } else {
        int o = atomicAdd(&counts[NB], 1);
        olist[o] = t;
    }
}

__global__ __launch_bounds__(256) void scatter_main(
    const float* __restrict__ W,
    const float* __restrict__ bias,
    const int*   __restrict__ counts,
    const int*   __restrict__ buckets,
    float*       __restrict__ out)
{
    // tile[el][vl] at stride 65 dwords: DMA-contiguous per row (64 dwords),
    // column reads hit banks (el + vl) % 32 -> worst 4-way on paired els.
    __shared__ float tile[ECH * 65];       // 33,280 B
    __shared__ int   toks[CAP];
    __shared__ int   s_cnt;

    int b     = blockIdx.x >> 1;           // bucket
    int panel = blockIdx.x & 1;            // e-panel
    int v0    = b * VB;
    int tid   = threadIdx.x;

    if (tid == 0) s_cnt = counts[b];
    if (tid < CAP) toks[tid] = buckets[b * CAP + tid];
    __syncthreads();
    int cnt = min(s_cnt, CAP);
    if (cnt == 0) return;

    int lane = tid & 63;
    int w    = tid >> 6;                   // wave id 0..3

    int vg = v0 + lane;
    size_t vclamp = (vg < VOCAB) ? (size_t)vg : (size_t)(VOCAB - 1);  // stay in-row

    for (int c = 0; c < EPB / ECH; ++c) {
        int e0 = panel * EPB + c * ECH;

        // ---- stage: one DMA instr per 256 B W-row run, 32 per wave ----
        #pragma unroll
        for (int p = 0; p < ECH / 4; ++p) {
            int r = p * 4 + w;             // row el
            const float* gp = W + (size_t)(e0 + r) * VOCAB + vclamp;
            float* lp = &tile[r * 65];     // wave-uniform base; dest = base + lane*4
            __builtin_amdgcn_global_load_lds(
                (const __attribute__((address_space(1))) void*)gp,
                (__attribute__((address_space(3))) void*)lp, 4, 0, 0);
        }
        __syncthreads();

        // ---- scatter: one wave per token, float2 (512 B/wave) stores ----
        int eL = e0 + 2 * lane;
        float2 bb = *reinterpret_cast<const float2*>(bias + eL);
        for (int i = w; i < cnt; i += 4) {
            int pk = toks[i];
            int t  = pk >> 6;
            int vl = pk & 63;
            float2 o;
            o.x = (tile[(2 * lane)     * 65 + vl] + bb.x) * SCALE;
            o.y = (tile[(2 * lane + 1) * 65 + vl] + bb.y) * SCALE;
            *reinterpret_cast<float2*>(out + (size_t)t * EMB + eL) = o;
        }
        __syncthreads();
    }
}

// Handles tokens whose bucket overflowed CAP (expected count: 0).
__global__ __launch_bounds__(256) void overflow_fix(
    const int*   __restrict__ counts,
    const int*   __restrict__ olist,
    const int*   __restrict__ ids,
    const float* __restrict__ W,
    const float* __restrict__ bias,
    float*       __restrict__ out)
{
    int n    = counts[NB];
    int wid  = (blockIdx.x * 256 + threadIdx.x) >> 6;
    int lane = threadIdx.x & 63;
    int nw   = (gridDim.x * 256) >> 6;
    for (int ww = wid; ww < n; ww += nw) {
        int t  = olist[ww];
        int id = ids[t];
        #pragma unroll
        for (int m = 0; m < 8; ++m) {
            int e = lane + m * 64;
            out[(size_t)t * EMB + e] = (W[(size_t)e * VOCAB + id] + bias[e]) * SCALE;
        }
    }
}

// Fallback (round-1 kernel) if d_ws is too small.
__global__ __launch_bounds__(256) void embed_gather(
    const int*   __restrict__ ids,
    const float* __restrict__ W,
    const float* __restrict__ b,
    float*       __restrict__ out)
{
    int idx4 = blockIdx.x * blockDim.x + threadIdx.x;
    int t    = idx4 >> 7;
    int e    = (idx4 & 127) << 2;
    int id = ids[t];
    float4 bb = *reinterpret_cast<const float4*>(b + e);
    const float* wcol = W + (size_t)id;
    float4 o;
    o.x = (wcol[(size_t)(e + 0) * VOCAB] + bb.x) * SCALE;
    o.y = (wcol[(size_t)(e + 1) * VOCAB] + bb.y) * SCALE;
    o.z = (wcol[(size_t)(e + 2) * VOCAB] + bb.z) * SCALE;
    o.w = (wcol[(size_t)(e + 3) * VOCAB] + bb.w) * SCALE;
    *reinterpret_cast<float4*>(out + (size_t)idx4 * 4) = o;
}

extern "C" void kernel_launch(void* const* d_in, const int* in_sizes, int n_in,
                              void* d_out, int out_size, void* d_ws, size_t ws_size,
                              hipStream_t stream)
{
    const int*   ids  = (const int*)  d_in[0];
    const float* W    = (const float*)d_in[1];
    const float* bias = (const float*)d_in[2];
    float*       out  = (float*)d_out;

    const size_t ws_ints_needed = (size_t)NB + 1 + NTOK + (size_t)NB * CAP;  // ~537 KB

    if (ws_size >= ws_ints_needed * sizeof(int)) {
        int* counts  = (int*)d_ws;
        int* olist   = counts + NB + 1;
        int* buckets = olist + NTOK;

        init_counts<<<(NB + 1 + 255) / 256, 256, 0, stream>>>(counts);
        build_buckets<<<NTOK / 256, 256, 0, stream>>>(ids, counts, olist, buckets);
        scatter_main<<<NB * 2, 256, 0, stream>>>(W, bias, counts, buckets, out);
        overflow_fix<<<32, 256, 0, stream>>>(counts, olist, ids, W, bias, out);
    } else {
        constexpr int total4 = NTOK * EMB / 4;
        embed_gather<<<total4 / 256, 256, 0, stream>>>(ids, W, bias, out);
    }
}